// Round 1
// baseline (396.353 us; speedup 1.0000x reference)
//
#include <hip/hip_runtime.h>

#define DEV __device__ __forceinline__

typedef short bf16x8 __attribute__((ext_vector_type(8)));
typedef float f32x4  __attribute__((ext_vector_type(4)));
typedef unsigned short u16;
typedef unsigned int u32;

// Problem constants: B=8, T=2048, D=1024, E=8, H=128
constexpr int MTOK = 16384;   // B*T
constexpr int DDIM = 1024;
constexpr int NEXP = 8;
constexpr int HDIM = 128;

// ---------- bf16 helpers (raw bit ops; RNE, no NaN in this data) ----------
DEV u16 f2bf(float f) {
  u32 u = __builtin_bit_cast(u32, f);
  u32 r = (u + 0x7FFFu + ((u >> 16) & 1u)) >> 16;
  return (u16)r;
}
DEV float bf2f(u16 s) {
  u32 u = ((u32)s) << 16;
  return __builtin_bit_cast(float, u);
}

DEV void async16(const void* g, void* l) {
  __builtin_amdgcn_global_load_lds(
      (const __attribute__((address_space(1))) void*)g,
      (__attribute__((address_space(3))) void*)l, 16, 0, 0);
}

// ---------------------------------------------------------------------------
// prep_x: one wave per token. Reads x row once; produces
//   x_hi/x_lo (bf16 split, [M,1024]) and probs[M,8] = softmax(x@Wr + br).
// ---------------------------------------------------------------------------
__global__ __launch_bounds__(256) void prep_x_kernel(
    const float* __restrict__ x, const float* __restrict__ Wr,
    const float* __restrict__ br,
    u16* __restrict__ xh, u16* __restrict__ xl, float* __restrict__ probs)
{
  const int wave = threadIdx.x >> 6, lane = threadIdx.x & 63;
  const int t = blockIdx.x * 4 + wave;
  const float* xr = x + (size_t)t * DDIM;

  float racc[8];
#pragma unroll
  for (int e = 0; e < 8; ++e) racc[e] = 0.f;

#pragma unroll
  for (int i = 0; i < 4; ++i) {
    const int d0 = i * 256 + lane * 4;
    float4 v = *(const float4*)(xr + d0);
    float vv[4] = {v.x, v.y, v.z, v.w};
    u16 hb[4], lb[4];
#pragma unroll
    for (int j = 0; j < 4; ++j) {
      u16 h = f2bf(vv[j]);
      hb[j] = h;
      lb[j] = f2bf(vv[j] - bf2f(h));
      const float4* w4 = (const float4*)(Wr + (size_t)(d0 + j) * 8);
      float4 w0 = w4[0], w1 = w4[1];
      racc[0] += vv[j] * w0.x; racc[1] += vv[j] * w0.y;
      racc[2] += vv[j] * w0.z; racc[3] += vv[j] * w0.w;
      racc[4] += vv[j] * w1.x; racc[5] += vv[j] * w1.y;
      racc[6] += vv[j] * w1.z; racc[7] += vv[j] * w1.w;
    }
    *(ushort4*)(xh + (size_t)t * DDIM + d0) = make_ushort4(hb[0], hb[1], hb[2], hb[3]);
    *(ushort4*)(xl + (size_t)t * DDIM + d0) = make_ushort4(lb[0], lb[1], lb[2], lb[3]);
  }

#pragma unroll
  for (int off = 32; off; off >>= 1)
#pragma unroll
    for (int e = 0; e < 8; ++e) racc[e] += __shfl_xor(racc[e], off, 64);

  float lg[8], mx = -1e30f;
#pragma unroll
  for (int e = 0; e < 8; ++e) { lg[e] = racc[e] + br[e]; mx = fmaxf(mx, lg[e]); }
  float ex[8], s = 0.f;
#pragma unroll
  for (int e = 0; e < 8; ++e) { ex[e] = expf(lg[e] - mx); s += ex[e]; }
  if (lane < 8) probs[(size_t)t * 8 + lane] = ex[lane] / s;
}

// ---------------------------------------------------------------------------
// transpose_split: dst[c][r] = src[r][c], fp32 -> bf16 hi/lo.
// Per-e block via blockIdx.z. src viewed [R][C] row-major at src+e*src_estride;
// dst element (c,r) at e*dst_estride + c*dst_stride + r.
// ---------------------------------------------------------------------------
__global__ __launch_bounds__(256) void transpose_split_kernel(
    const float* __restrict__ src, u16* __restrict__ dh, u16* __restrict__ dl,
    int C, size_t src_estride, size_t dst_estride, int dst_stride)
{
  const int e = blockIdx.z;
  src += (size_t)e * src_estride;
  const size_t doff = (size_t)e * dst_estride;
  const int c0 = blockIdx.x * 32, r0 = blockIdx.y * 32;
  __shared__ float tl[32][33];
  const int tx = threadIdx.x & 31, ty = threadIdx.x >> 5;   // ty: 0..7
#pragma unroll
  for (int i = 0; i < 4; ++i)
    tl[ty + i * 8][tx] = src[(size_t)(r0 + ty + i * 8) * C + c0 + tx];
  __syncthreads();
#pragma unroll
  for (int i = 0; i < 4; ++i) {
    float v = tl[tx][ty + i * 8];
    u16 h = f2bf(v);
    u16 l = f2bf(v - bf2f(h));
    size_t o = doff + (size_t)(c0 + ty + i * 8) * dst_stride + r0 + tx;
    dh[o] = h; dl[o] = l;
  }
}

// ---------------------------------------------------------------------------
// Split-bf16 GEMM: C[M=16384, N=1024] = A[M,K=1024] * B[K,N], with A given as
// hi/lo bf16 [M,K] row-major and B given as hi/lo bf16 B^T [N,K] row-major.
// acc += Ah*Bh + Ah*Bl + Al*Bh   (fp32 MFMA accumulate).
// EPI=0: val = gelu(acc + bd[n]) * probs[m, n>>7] -> split-store gp hi/lo.
// EPI=1: out[m,n] = acc + sum_e probs[m,e]*bu[e,n]  (fp32 store).
// ---------------------------------------------------------------------------
constexpr int BM = 128, BN = 128, BK = 64;

template <int EPI>
__global__ __launch_bounds__(256, 2) void gemm_split_kernel(
    const u16* __restrict__ Ah, const u16* __restrict__ Al,
    const u16* __restrict__ Bh, const u16* __restrict__ Bl,
    const float* __restrict__ bias, const float* __restrict__ probs,
    u16* __restrict__ oh, u16* __restrict__ ol, float* __restrict__ of)
{
  __shared__ u16 sAh[BM * BK], sAl[BM * BK], sBh[BN * BK], sBl[BN * BK];
  const int tid = threadIdx.x;
  const int lane = tid & 63, wave = tid >> 6;
  const int wr = wave >> 1, wc = wave & 1;
  const int m0 = blockIdx.x * BM, n0 = blockIdx.y * BN;
  const int srow = tid >> 3;          // 0..31
  const int scol = (tid & 7) * 8;     // ushort col within BK
  const int fr = lane & 15, fq = lane >> 4;

  f32x4 acc[4][4] = {};

  for (int kt = 0; kt < DDIM; kt += BK) {
#pragma unroll
    for (int i = 0; i < 4; ++i) {
      const int r = i * 32 + srow;
      const size_t ga = (size_t)(m0 + r) * DDIM + kt + scol;
      const size_t gb = (size_t)(n0 + r) * DDIM + kt + scol;
      const int lo = r * BK + scol;
      async16(Ah + ga, sAh + lo);
      async16(Al + ga, sAl + lo);
      async16(Bh + gb, sBh + lo);
      async16(Bl + gb, sBl + lo);
    }
    __syncthreads();
#pragma unroll
    for (int kk = 0; kk < BK; kk += 32) {
      const int koff = kk + fq * 8;
      bf16x8 ah[4], al[4], bh[4], bl[4];
#pragma unroll
      for (int mi = 0; mi < 4; ++mi) {
        const int row = wr * 64 + mi * 16 + fr;
        ah[mi] = *(const bf16x8*)&sAh[row * BK + koff];
        al[mi] = *(const bf16x8*)&sAl[row * BK + koff];
      }
#pragma unroll
      for (int ni = 0; ni < 4; ++ni) {
        const int row = wc * 64 + ni * 16 + fr;
        bh[ni] = *(const bf16x8*)&sBh[row * BK + koff];
        bl[ni] = *(const bf16x8*)&sBl[row * BK + koff];
      }
#pragma unroll
      for (int mi = 0; mi < 4; ++mi)
#pragma unroll
        for (int ni = 0; ni < 4; ++ni) {
          f32x4 c = acc[mi][ni];
          c = __builtin_amdgcn_mfma_f32_16x16x32_bf16(ah[mi], bh[ni], c, 0, 0, 0);
          c = __builtin_amdgcn_mfma_f32_16x16x32_bf16(ah[mi], bl[ni], c, 0, 0, 0);
          c = __builtin_amdgcn_mfma_f32_16x16x32_bf16(al[mi], bh[ni], c, 0, 0, 0);
          acc[mi][ni] = c;
        }
    }
    __syncthreads();
  }

  if (EPI == 0) {
#pragma unroll
    for (int mi = 0; mi < 4; ++mi)
#pragma unroll
      for (int ni = 0; ni < 4; ++ni) {
        const int colg = n0 + wc * 64 + ni * 16 + fr;
        const float bv = bias[colg];          // bd flat [1024]
        const int e = colg >> 7;              // expert = col/128
#pragma unroll
        for (int j = 0; j < 4; ++j) {
          const int rowg = m0 + wr * 64 + mi * 16 + fq * 4 + j;
          float v = acc[mi][ni][j] + bv;
          float g = 0.5f * v * (1.0f + erff(v * 0.70710678118654752f));
          float q = probs[(size_t)rowg * 8 + e] * g;
          u16 h = f2bf(q);
          u16 l = f2bf(q - bf2f(h));
          const size_t o = (size_t)rowg * 1024 + colg;
          oh[o] = h; ol[o] = l;
        }
      }
  } else {
    float buv[4][8];
#pragma unroll
    for (int ni = 0; ni < 4; ++ni) {
      const int colg = n0 + wc * 64 + ni * 16 + fr;
#pragma unroll
      for (int e = 0; e < 8; ++e) buv[ni][e] = bias[e * 1024 + colg];  // bu[E,D]
    }
#pragma unroll
    for (int mi = 0; mi < 4; ++mi)
#pragma unroll
      for (int j = 0; j < 4; ++j) {
        const int rowg = m0 + wr * 64 + mi * 16 + fq * 4 + j;
        const float4* pp = (const float4*)(probs + (size_t)rowg * 8);
        float4 p0 = pp[0], p1 = pp[1];
        float pr[8] = {p0.x, p0.y, p0.z, p0.w, p1.x, p1.y, p1.z, p1.w};
#pragma unroll
        for (int ni = 0; ni < 4; ++ni) {
          float v = acc[mi][ni][j];
#pragma unroll
          for (int e = 0; e < 8; ++e) v += pr[e] * buv[ni][e];
          of[(size_t)rowg * 1024 + n0 + wc * 64 + ni * 16 + fr] = v;
        }
      }
  }
}

// ---------------------------------------------------------------------------
extern "C" void kernel_launch(void* const* d_in, const int* in_sizes, int n_in,
                              void* d_out, int out_size, void* d_ws, size_t ws_size,
                              hipStream_t stream)
{
  const float* x  = (const float*)d_in[0];
  const float* Wr = (const float*)d_in[1];
  const float* br = (const float*)d_in[2];
  const float* Wd = (const float*)d_in[3];
  const float* bd = (const float*)d_in[4];   // [E,H] == flat [1024] in (e*H+h)
  const float* Wu = (const float*)d_in[5];
  const float* bu = (const float*)d_in[6];   // [E,D]
  float* out = (float*)d_out;

  char* ws = (char*)d_ws;
  size_t off = 0;
  auto alloc = [&](size_t bytes) -> void* {
    void* p = ws + off;
    off += (bytes + 255) & ~(size_t)255;
    return p;
  };
  u16* xh  = (u16*)alloc((size_t)MTOK * DDIM * 2);
  u16* xl  = (u16*)alloc((size_t)MTOK * DDIM * 2);
  u16* gph = (u16*)alloc((size_t)MTOK * 1024 * 2);
  u16* gpl = (u16*)alloc((size_t)MTOK * 1024 * 2);
  u16* bdh = (u16*)alloc((size_t)1024 * 1024 * 2);
  u16* bdl = (u16*)alloc((size_t)1024 * 1024 * 2);
  u16* wuh = (u16*)alloc((size_t)1024 * 1024 * 2);
  u16* wul = (u16*)alloc((size_t)1024 * 1024 * 2);
  float* probs = (float*)alloc((size_t)MTOK * 8 * 4);
  (void)ws_size; (void)in_sizes; (void)n_in; (void)out_size;

  // Router softmax + x hi/lo split (single pass over x).
  prep_x_kernel<<<MTOK / 4, 256, 0, stream>>>(x, Wr, br, xh, xl, probs);

  // Wd [E,D,H] -> BdT[n=e*128+h][k=d]  (per-e transpose of [1024,128])
  transpose_split_kernel<<<dim3(4, 32, 8), 256, 0, stream>>>(
      Wd, bdh, bdl, /*C=*/HDIM, /*src_estride=*/(size_t)DDIM * HDIM,
      /*dst_estride=*/(size_t)HDIM * 1024, /*dst_stride=*/1024);

  // Wu [E,H,D] -> WuT[n=d][k=e*128+h]  (per-e transpose of [128,1024])
  transpose_split_kernel<<<dim3(32, 4, 8), 256, 0, stream>>>(
      Wu, wuh, wul, /*C=*/DDIM, /*src_estride=*/(size_t)HDIM * DDIM,
      /*dst_estride=*/(size_t)HDIM, /*dst_stride=*/1024);

  // GEMM1: down = x @ Wd ; gp = probs * gelu(down + bd)  -> hi/lo bf16
  gemm_split_kernel<0><<<dim3(MTOK / BM, 1024 / BN), 256, 0, stream>>>(
      xh, xl, bdh, bdl, bd, probs, gph, gpl, nullptr);

  // GEMM2: out = gp @ Wu + sum_e probs_e * bu[e,:]
  gemm_split_kernel<1><<<dim3(MTOK / BM, 1024 / BN), 256, 0, stream>>>(
      gph, gpl, wuh, wul, bu, probs, nullptr, nullptr, out);
}

// Round 2
// 302.369 us; speedup vs baseline: 1.3108x; 1.3108x over previous
//
#include <hip/hip_runtime.h>

#define DEV __device__ __forceinline__

typedef short bf16x8 __attribute__((ext_vector_type(8)));
typedef float f32x4  __attribute__((ext_vector_type(4)));
typedef unsigned short u16;
typedef unsigned int u32;

// Problem constants: B=8, T=2048, D=1024, E=8, H=128
constexpr int MTOK = 16384;   // B*T
constexpr int DDIM = 1024;
constexpr int HDIM = 128;

// ---------- bf16 helpers (RNE) ----------
DEV u16 f2bf(float f) {
  u32 u = __builtin_bit_cast(u32, f);
  u32 r = (u + 0x7FFFu + ((u >> 16) & 1u)) >> 16;
  return (u16)r;
}
DEV float bf2f(u16 s) {
  u32 u = ((u32)s) << 16;
  return __builtin_bit_cast(float, u);
}

DEV void async16(const void* g, void* l) {
  __builtin_amdgcn_global_load_lds(
      (const __attribute__((address_space(1))) void*)g,
      (__attribute__((address_space(3))) void*)l, 16, 0, 0);
}

// ---------------------------------------------------------------------------
// prep_x: one wave per token. Reads x row once; produces x bf16 [M,1024] and
// probs[M,8] = softmax(x@Wr + br).
// ---------------------------------------------------------------------------
__global__ __launch_bounds__(256) void prep_x_kernel(
    const float* __restrict__ x, const float* __restrict__ Wr,
    const float* __restrict__ br,
    u16* __restrict__ xh, float* __restrict__ probs)
{
  const int wave = threadIdx.x >> 6, lane = threadIdx.x & 63;
  const int t = blockIdx.x * 4 + wave;
  const float* xr = x + (size_t)t * DDIM;

  float racc[8];
#pragma unroll
  for (int e = 0; e < 8; ++e) racc[e] = 0.f;

#pragma unroll
  for (int i = 0; i < 4; ++i) {
    const int d0 = i * 256 + lane * 4;
    float4 v = *(const float4*)(xr + d0);
    float vv[4] = {v.x, v.y, v.z, v.w};
    u16 hb[4];
#pragma unroll
    for (int j = 0; j < 4; ++j) {
      hb[j] = f2bf(vv[j]);
      const float4* w4 = (const float4*)(Wr + (size_t)(d0 + j) * 8);
      float4 w0 = w4[0], w1 = w4[1];
      racc[0] += vv[j] * w0.x; racc[1] += vv[j] * w0.y;
      racc[2] += vv[j] * w0.z; racc[3] += vv[j] * w0.w;
      racc[4] += vv[j] * w1.x; racc[5] += vv[j] * w1.y;
      racc[6] += vv[j] * w1.z; racc[7] += vv[j] * w1.w;
    }
    *(ushort4*)(xh + (size_t)t * DDIM + d0) = make_ushort4(hb[0], hb[1], hb[2], hb[3]);
  }

#pragma unroll
  for (int off = 32; off; off >>= 1)
#pragma unroll
    for (int e = 0; e < 8; ++e) racc[e] += __shfl_xor(racc[e], off, 64);

  float lg[8], mx = -1e30f;
#pragma unroll
  for (int e = 0; e < 8; ++e) { lg[e] = racc[e] + br[e]; mx = fmaxf(mx, lg[e]); }
  float ex[8], s = 0.f;
#pragma unroll
  for (int e = 0; e < 8; ++e) { ex[e] = expf(lg[e] - mx); s += ex[e]; }
  if (lane < 8) probs[(size_t)t * 8 + lane] = ex[lane] / s;
}

// ---------------------------------------------------------------------------
// transpose_bf16: dst[c][r] = (bf16)src[r][c]. Per-e block via blockIdx.z.
// src viewed [R][C] row-major at src+e*src_estride; dst element (c,r) at
// e*dst_estride + c*dst_stride + r.
// ---------------------------------------------------------------------------
__global__ __launch_bounds__(256) void transpose_bf16_kernel(
    const float* __restrict__ src, u16* __restrict__ dh,
    int C, size_t src_estride, size_t dst_estride, int dst_stride)
{
  const int e = blockIdx.z;
  src += (size_t)e * src_estride;
  const size_t doff = (size_t)e * dst_estride;
  const int c0 = blockIdx.x * 32, r0 = blockIdx.y * 32;
  __shared__ float tl[32][33];
  const int tx = threadIdx.x & 31, ty = threadIdx.x >> 5;   // ty: 0..7
#pragma unroll
  for (int i = 0; i < 4; ++i)
    tl[ty + i * 8][tx] = src[(size_t)(r0 + ty + i * 8) * C + c0 + tx];
  __syncthreads();
#pragma unroll
  for (int i = 0; i < 4; ++i) {
    float v = tl[tx][ty + i * 8];
    size_t o = doff + (size_t)(c0 + ty + i * 8) * dst_stride + r0 + tx;
    dh[o] = f2bf(v);
  }
}

// ---------------------------------------------------------------------------
// bf16 GEMM (m97 structure): C[M=16384, N=1024] = A[M,K=1024] * B[K,N],
// A bf16 [M,K] row-major, B bf16 B^T [N,K] row-major.
// EPI=0: val = gelu(acc + bd[n]) * probs[m, n>>7] -> bf16 store (gp).
// EPI=1: out[m,n] = acc + sum_e probs[m,e]*bu[e,n]  (fp32 store).
// ---------------------------------------------------------------------------
constexpr int BM = 128, BN = 128, BK = 64;

template <int EPI>
__global__ __launch_bounds__(256, 2) void gemm_bf16_kernel(
    const u16* __restrict__ A, const u16* __restrict__ B,
    const float* __restrict__ bias, const float* __restrict__ probs,
    u16* __restrict__ ogp, float* __restrict__ of)
{
  __shared__ u16 sA[BM * BK], sB[BN * BK];
  const int tid = threadIdx.x;
  const int lane = tid & 63, wave = tid >> 6;
  const int wr = wave >> 1, wc = wave & 1;
  const int m0 = blockIdx.x * BM, n0 = blockIdx.y * BN;
  const int srow = tid >> 3;          // 0..31
  const int scol = (tid & 7) * 8;     // ushort col within BK
  const int fr = lane & 15, fq = lane >> 4;

  f32x4 acc[4][4] = {};

  for (int kt = 0; kt < DDIM; kt += BK) {
#pragma unroll
    for (int i = 0; i < 4; ++i) {
      const int r = i * 32 + srow;
      const size_t ga = (size_t)(m0 + r) * DDIM + kt + scol;
      const size_t gb = (size_t)(n0 + r) * DDIM + kt + scol;
      const int lo = r * BK + scol;
      async16(A + ga, sA + lo);
      async16(B + gb, sB + lo);
    }
    __syncthreads();
#pragma unroll
    for (int kk = 0; kk < BK; kk += 32) {
      const int koff = kk + fq * 8;
      bf16x8 av[4], bv[4];
#pragma unroll
      for (int mi = 0; mi < 4; ++mi) {
        const int row = wr * 64 + mi * 16 + fr;
        av[mi] = *(const bf16x8*)&sA[row * BK + koff];
      }
#pragma unroll
      for (int ni = 0; ni < 4; ++ni) {
        const int row = wc * 64 + ni * 16 + fr;
        bv[ni] = *(const bf16x8*)&sB[row * BK + koff];
      }
#pragma unroll
      for (int mi = 0; mi < 4; ++mi)
#pragma unroll
        for (int ni = 0; ni < 4; ++ni)
          acc[mi][ni] = __builtin_amdgcn_mfma_f32_16x16x32_bf16(
              av[mi], bv[ni], acc[mi][ni], 0, 0, 0);
    }
    __syncthreads();
  }

  if (EPI == 0) {
#pragma unroll
    for (int mi = 0; mi < 4; ++mi)
#pragma unroll
      for (int ni = 0; ni < 4; ++ni) {
        const int colg = n0 + wc * 64 + ni * 16 + fr;
        const float bv = bias[colg];          // bd flat [1024]
        const int e = colg >> 7;              // expert = col/128
#pragma unroll
        for (int j = 0; j < 4; ++j) {
          const int rowg = m0 + wr * 64 + mi * 16 + fq * 4 + j;
          float v = acc[mi][ni][j] + bv;
          float g = 0.5f * v * (1.0f + erff(v * 0.70710678118654752f));
          float q = probs[(size_t)rowg * 8 + e] * g;
          ogp[(size_t)rowg * 1024 + colg] = f2bf(q);
        }
      }
  } else {
    float buv[4][8];
#pragma unroll
    for (int ni = 0; ni < 4; ++ni) {
      const int colg = n0 + wc * 64 + ni * 16 + fr;
#pragma unroll
      for (int e = 0; e < 8; ++e) buv[ni][e] = bias[e * 1024 + colg];  // bu[E,D]
    }
#pragma unroll
    for (int mi = 0; mi < 4; ++mi)
#pragma unroll
      for (int j = 0; j < 4; ++j) {
        const int rowg = m0 + wr * 64 + mi * 16 + fq * 4 + j;
        const float4* pp = (const float4*)(probs + (size_t)rowg * 8);
        float4 p0 = pp[0], p1 = pp[1];
        float pr[8] = {p0.x, p0.y, p0.z, p0.w, p1.x, p1.y, p1.z, p1.w};
#pragma unroll
        for (int ni = 0; ni < 4; ++ni) {
          float v = acc[mi][ni][j];
#pragma unroll
          for (int e = 0; e < 8; ++e) v += pr[e] * buv[ni][e];
          of[(size_t)rowg * 1024 + n0 + wc * 64 + ni * 16 + fr] = v;
        }
      }
  }
}

// ---------------------------------------------------------------------------
extern "C" void kernel_launch(void* const* d_in, const int* in_sizes, int n_in,
                              void* d_out, int out_size, void* d_ws, size_t ws_size,
                              hipStream_t stream)
{
  const float* x  = (const float*)d_in[0];
  const float* Wr = (const float*)d_in[1];
  const float* br = (const float*)d_in[2];
  const float* Wd = (const float*)d_in[3];
  const float* bd = (const float*)d_in[4];   // [E,H] == flat [1024]
  const float* Wu = (const float*)d_in[5];
  const float* bu = (const float*)d_in[6];   // [E,D]
  float* out = (float*)d_out;

  char* ws = (char*)d_ws;
  size_t off = 0;
  auto alloc = [&](size_t bytes) -> void* {
    void* p = ws + off;
    off += (bytes + 255) & ~(size_t)255;
    return p;
  };
  u16* xh  = (u16*)alloc((size_t)MTOK * DDIM * 2);
  u16* gph = (u16*)alloc((size_t)MTOK * 1024 * 2);
  u16* bdh = (u16*)alloc((size_t)1024 * 1024 * 2);
  u16* wuh = (u16*)alloc((size_t)1024 * 1024 * 2);
  float* probs = (float*)alloc((size_t)MTOK * 8 * 4);
  (void)ws_size; (void)in_sizes; (void)n_in; (void)out_size;

  // Router softmax + x bf16 cast (single pass over x).
  prep_x_kernel<<<MTOK / 4, 256, 0, stream>>>(x, Wr, br, xh, probs);

  // Wd [E,D,H] -> BdT[n=e*128+h][k=d]
  transpose_bf16_kernel<<<dim3(4, 32, 8), 256, 0, stream>>>(
      Wd, bdh, /*C=*/HDIM, /*src_estride=*/(size_t)DDIM * HDIM,
      /*dst_estride=*/(size_t)HDIM * 1024, /*dst_stride=*/1024);

  // Wu [E,H,D] -> WuT[n=d][k=e*128+h]
  transpose_bf16_kernel<<<dim3(32, 4, 8), 256, 0, stream>>>(
      Wu, wuh, /*C=*/DDIM, /*src_estride=*/(size_t)HDIM * DDIM,
      /*dst_estride=*/(size_t)HDIM, /*dst_stride=*/1024);

  // GEMM1: down = x @ Wd ; gp = probs * gelu(down + bd)  -> bf16
  gemm_bf16_kernel<0><<<dim3(MTOK / BM, 1024 / BN), 256, 0, stream>>>(
      xh, bdh, bd, probs, gph, nullptr);

  // GEMM2: out = gp @ Wu + sum_e probs_e * bu[e,:]
  gemm_bf16_kernel<1><<<dim3(MTOK / BM, 1024 / BN), 256, 0, stream>>>(
      gph, wuh, bu, probs, nullptr, out);
}

// Round 3
// 287.915 us; speedup vs baseline: 1.3766x; 1.0502x over previous
//
#include <hip/hip_runtime.h>

#define DEV __device__ __forceinline__

typedef short bf16x8 __attribute__((ext_vector_type(8)));
typedef float f32x4  __attribute__((ext_vector_type(4)));
typedef unsigned short u16;
typedef unsigned int u32;

// Problem constants: B=8, T=2048, D=1024, E=8, H=128
constexpr int MTOK = 16384;
constexpr int DDIM = 1024;
constexpr int HDIM = 128;

// GEMM geometry
constexpr int BM = 256, BN = 128, BK = 64;
constexpr int NKT = DDIM / BK;       // 16 K-tiles
constexpr int TA = BM * BK * 2;      // A tile bytes  (32768)
constexpr int TB = BN * BK * 2;      // B tile bytes  (16384)
constexpr int TT = TA + TB;          // tile bytes    (49152); 3 bufs = 144 KiB

DEV u16 f2bf(float f) {
  u32 u = __builtin_bit_cast(u32, f);
  return (u16)((u + 0x7FFFu + ((u >> 16) & 1u)) >> 16);
}

DEV void async16(const void* g, void* l) {
  __builtin_amdgcn_global_load_lds(
      (const __attribute__((address_space(1))) void*)g,
      (__attribute__((address_space(3))) void*)l, 16, 0, 0);
}

// ---------------------------------------------------------------------------
// prep_all: one kernel, three block roles.
//   bid <  4096 : prep_x   — x row -> bf16 + router softmax probs
//   bid <  5120 : Wd [E,D,H] -> BdT[(e*128+h)][d]   bf16
//   else        : Wu [E,H,D] -> WuT[d][(e*128+h)]   bf16
// ---------------------------------------------------------------------------
__global__ __launch_bounds__(256) void prep_all_kernel(
    const float* __restrict__ x, const float* __restrict__ Wr,
    const float* __restrict__ br, const float* __restrict__ Wd,
    const float* __restrict__ Wu,
    u16* __restrict__ xh, u16* __restrict__ bdh, u16* __restrict__ wuh,
    float* __restrict__ probs)
{
  __shared__ float tl[32][33];
  const int bid = blockIdx.x;

  if (bid < 4096) {
    const int wave = threadIdx.x >> 6, lane = threadIdx.x & 63;
    const int t = bid * 4 + wave;
    const float* xr = x + (size_t)t * DDIM;

    float racc[8];
#pragma unroll
    for (int e = 0; e < 8; ++e) racc[e] = 0.f;

#pragma unroll
    for (int i = 0; i < 4; ++i) {
      const int d0 = i * 256 + lane * 4;
      float4 v = *(const float4*)(xr + d0);
      float vv[4] = {v.x, v.y, v.z, v.w};
      u16 hb[4];
#pragma unroll
      for (int j = 0; j < 4; ++j) {
        hb[j] = f2bf(vv[j]);
        const float4* w4 = (const float4*)(Wr + (size_t)(d0 + j) * 8);
        float4 w0 = w4[0], w1 = w4[1];
        racc[0] += vv[j] * w0.x; racc[1] += vv[j] * w0.y;
        racc[2] += vv[j] * w0.z; racc[3] += vv[j] * w0.w;
        racc[4] += vv[j] * w1.x; racc[5] += vv[j] * w1.y;
        racc[6] += vv[j] * w1.z; racc[7] += vv[j] * w1.w;
      }
      *(ushort4*)(xh + (size_t)t * DDIM + d0) = make_ushort4(hb[0], hb[1], hb[2], hb[3]);
    }

#pragma unroll
    for (int off = 32; off; off >>= 1)
#pragma unroll
      for (int e = 0; e < 8; ++e) racc[e] += __shfl_xor(racc[e], off, 64);

    float lg[8], mx = -1e30f;
#pragma unroll
    for (int e = 0; e < 8; ++e) { lg[e] = racc[e] + br[e]; mx = fmaxf(mx, lg[e]); }
    float ex[8], s = 0.f;
#pragma unroll
    for (int e = 0; e < 8; ++e) { ex[e] = expf(lg[e] - mx); s += ex[e]; }
    if (lane < 8) probs[(size_t)t * 8 + lane] = ex[lane] / s;
    return;
  }

  // ---- transpose roles ----
  const float* src; u16* dst; int C; size_t dbase; int c0, r0;
  if (bid < 5120) {
    const int l = bid - 4096, e = l >> 7;
    src = Wd + (size_t)e * DDIM * HDIM; C = HDIM;
    dst = bdh; dbase = (size_t)e * HDIM * 1024;
    c0 = (l & 3) * 32; r0 = ((l >> 2) & 31) * 32;
  } else {
    const int l = bid - 5120, e = l >> 7;
    src = Wu + (size_t)e * HDIM * DDIM; C = DDIM;
    dst = wuh; dbase = (size_t)e * HDIM;
    c0 = (l & 31) * 32; r0 = ((l >> 5) & 3) * 32;
  }
  const int tx = threadIdx.x & 31, ty = threadIdx.x >> 5;
#pragma unroll
  for (int i = 0; i < 4; ++i)
    tl[ty + i * 8][tx] = src[(size_t)(r0 + ty + i * 8) * C + c0 + tx];
  __syncthreads();
#pragma unroll
  for (int i = 0; i < 4; ++i) {
    float v = tl[tx][ty + i * 8];
    dst[dbase + (size_t)(c0 + ty + i * 8) * 1024 + r0 + tx] = f2bf(v);
  }
}

// ---------------------------------------------------------------------------
// Pipelined bf16 GEMM: C[M=16384, N=1024] = A[M,K=1024] * B^T[N,K].
// 3-stage LDS pipeline, counted vmcnt(6) (never 0 in loop), 1 barrier/K-tile,
// XOR-16B chunk swizzle (involution: inverse-swz global source, swz ds_read),
// setprio around MFMA cluster, XCD-aware block swizzle (each XCD owns 1 N-tile).
// EPI=0: gp = probs[m, n>>7] * gelu(acc + bd[n]) -> bf16
// EPI=1: out = acc + sum_e probs[m,e]*bu[e,n]    -> fp32
// ---------------------------------------------------------------------------
template <int EPI>
__global__ __launch_bounds__(512, 2) void gemm_bf16_kernel(
    const u16* __restrict__ A, const u16* __restrict__ B,
    const float* __restrict__ bias, const float* __restrict__ probs,
    u16* __restrict__ ogp, float* __restrict__ of)
{
  __shared__ __align__(128) u16 lds[3 * TT / 2];   // 147456 bytes
  const int tid = threadIdx.x, lane = tid & 63, wave = tid >> 6;
  const int wm = wave >> 1, wn = wave & 1;          // 4 M-waves x 2 N-waves
  const int fr = lane & 15, fq = lane >> 4;

  // XCD swizzle: 512 blocks, 8 XCDs -> XCD x owns N-tile x (B panel L2-resident)
  const int swz = (blockIdx.x & 7) * 64 + (blockIdx.x >> 3);
  const int n0 = (swz >> 6) * BN;
  const int m0 = (swz & 63) * BM;

  // Stage K-tile t into buf[t%3]. LDS dest linear (tid*16); global source
  // chunk-XOR'd so that a swizzled ds_read returns logical data.
  auto stage = [&](int t) {
    u16* buf = lds + (size_t)(t % 3) * (TT / 2);
    const int kt = t * BK;
#pragma unroll
    for (int r = 0; r < 4; ++r) {
      const int off = r * 8192 + tid * 16;
      const int row = off >> 7, c = (off >> 4) & 7;
      const int sc = c ^ (row & 7);
      async16(A + (size_t)(m0 + row) * DDIM + kt + sc * 8, (char*)buf + off);
    }
#pragma unroll
    for (int r = 0; r < 2; ++r) {
      const int off = r * 8192 + tid * 16;
      const int row = off >> 7, c = (off >> 4) & 7;
      const int sc = c ^ (row & 7);
      async16(B + (size_t)(n0 + row) * DDIM + kt + sc * 8, (char*)buf + TA + off);
    }
  };

  f32x4 acc[4][4] = {};

  // Prologue: tiles 0,1 staged; force tile 0 landed (tile 1's 6 stay in flight).
  stage(0);
  stage(1);
  asm volatile("s_waitcnt vmcnt(6)" ::: "memory");
  __builtin_amdgcn_s_barrier();
  __builtin_amdgcn_sched_barrier(0);

  for (int t = 0; t < NKT; ++t) {
    if (t + 2 < NKT) stage(t + 2);   // writes buf[(t-1)%3]: idle since end of t-1

    const u16* At = lds + (size_t)(t % 3) * (TT / 2);
    const u16* Bt = At + TA / 2;
    bf16x8 a[2][4], b[2][4];
#pragma unroll
    for (int k2 = 0; k2 < 2; ++k2) {
      const int koff = k2 * 32 + fq * 8;
#pragma unroll
      for (int mi = 0; mi < 4; ++mi) {
        const int row = wm * 64 + mi * 16 + fr;
        int byt = (row << 7) + (koff << 1); byt ^= (row & 7) << 4;
        a[k2][mi] = *(const bf16x8*)((const char*)At + byt);
      }
#pragma unroll
      for (int ni = 0; ni < 4; ++ni) {
        const int row = wn * 64 + ni * 16 + fr;
        int byt = (row << 7) + (koff << 1); byt ^= (row & 7) << 4;
        b[k2][ni] = *(const bf16x8*)((const char*)Bt + byt);
      }
    }
    __builtin_amdgcn_s_setprio(1);
#pragma unroll
    for (int k2 = 0; k2 < 2; ++k2)
#pragma unroll
      for (int mi = 0; mi < 4; ++mi)
#pragma unroll
        for (int ni = 0; ni < 4; ++ni)
          acc[mi][ni] = __builtin_amdgcn_mfma_f32_16x16x32_bf16(
              a[k2][mi], b[k2][ni], acc[mi][ni], 0, 0, 0);
    __builtin_amdgcn_s_setprio(0);
    __builtin_amdgcn_sched_barrier(0);
    // Force tile t+1 landed; tile t+2's 6 loads may remain in flight.
    if (t < NKT - 2) asm volatile("s_waitcnt vmcnt(6)" ::: "memory");
    else             asm volatile("s_waitcnt vmcnt(0)" ::: "memory");
    __builtin_amdgcn_s_barrier();
    __builtin_amdgcn_sched_barrier(0);
  }

  if (EPI == 0) {
#pragma unroll
    for (int mi = 0; mi < 4; ++mi)
#pragma unroll
      for (int ni = 0; ni < 4; ++ni) {
        const int col = n0 + wn * 64 + ni * 16 + fr;
        const float bv = bias[col];            // bd flat [1024] = (e*H+h)
        const int e = col >> 7;
#pragma unroll
        for (int j = 0; j < 4; ++j) {
          const int row = m0 + wm * 64 + mi * 16 + fq * 4 + j;
          float v = acc[mi][ni][j] + bv;
          float g = 0.5f * v * (1.0f + erff(v * 0.70710678118654752f));
          ogp[(size_t)row * DDIM + col] = f2bf(probs[(size_t)row * 8 + e] * g);
        }
      }
  } else {
    float buv[4][8];
#pragma unroll
    for (int ni = 0; ni < 4; ++ni) {
      const int col = n0 + wn * 64 + ni * 16 + fr;
#pragma unroll
      for (int e = 0; e < 8; ++e) buv[ni][e] = bias[e * 1024 + col];  // bu[E,D]
    }
#pragma unroll
    for (int mi = 0; mi < 4; ++mi)
#pragma unroll
      for (int j = 0; j < 4; ++j) {
        const int row = m0 + wm * 64 + mi * 16 + fq * 4 + j;
        const float4* pp = (const float4*)(probs + (size_t)row * 8);
        float4 p0 = pp[0], p1 = pp[1];
        float pr[8] = {p0.x, p0.y, p0.z, p0.w, p1.x, p1.y, p1.z, p1.w};
#pragma unroll
        for (int ni = 0; ni < 4; ++ni) {
          float v = acc[mi][ni][j];
#pragma unroll
          for (int e = 0; e < 8; ++e) v += pr[e] * buv[ni][e];
          of[(size_t)row * DDIM + n0 + wn * 64 + ni * 16 + fr] = v;
        }
      }
  }
}

// ---------------------------------------------------------------------------
extern "C" void kernel_launch(void* const* d_in, const int* in_sizes, int n_in,
                              void* d_out, int out_size, void* d_ws, size_t ws_size,
                              hipStream_t stream)
{
  const float* x  = (const float*)d_in[0];
  const float* Wr = (const float*)d_in[1];
  const float* br = (const float*)d_in[2];
  const float* Wd = (const float*)d_in[3];
  const float* bd = (const float*)d_in[4];
  const float* Wu = (const float*)d_in[5];
  const float* bu = (const float*)d_in[6];
  float* out = (float*)d_out;

  char* ws = (char*)d_ws;
  size_t off = 0;
  auto alloc = [&](size_t bytes) -> void* {
    void* p = ws + off;
    off += (bytes + 255) & ~(size_t)255;
    return p;
  };
  u16* xh  = (u16*)alloc((size_t)MTOK * DDIM * 2);
  u16* gph = (u16*)alloc((size_t)MTOK * 1024 * 2);
  u16* bdh = (u16*)alloc((size_t)1024 * 1024 * 2);
  u16* wuh = (u16*)alloc((size_t)1024 * 1024 * 2);
  float* probs = (float*)alloc((size_t)MTOK * 8 * 4);
  (void)ws_size; (void)in_sizes; (void)n_in; (void)out_size;

  prep_all_kernel<<<6144, 256, 0, stream>>>(x, Wr, br, Wd, Wu, xh, bdh, wuh, probs);

  gemm_bf16_kernel<0><<<512, 512, 0, stream>>>(xh, bdh, bd, probs, gph, nullptr);
  gemm_bf16_kernel<1><<<512, 512, 0, stream>>>(gph, wuh, bu, probs, nullptr, out);
}

// Round 5
// 242.007 us; speedup vs baseline: 1.6378x; 1.1897x over previous
//
#include <hip/hip_runtime.h>

#define DEV __device__ __forceinline__

typedef short bf16x8 __attribute__((ext_vector_type(8)));
typedef float f32x4  __attribute__((ext_vector_type(4)));
typedef unsigned short u16;
typedef unsigned int u32;

constexpr int MTOK = 16384;
constexpr int DDIM = 1024;
constexpr int BK = 64;
constexpr int NKT = DDIM / BK;   // 16

DEV u16 f2bf(float f) {
  u32 u = __builtin_bit_cast(u32, f);
  return (u16)((u + 0x7FFFu + ((u >> 16) & 1u)) >> 16);
}

DEV void async16(const void* g, void* l) {
  __builtin_amdgcn_global_load_lds(
      (const __attribute__((address_space(1))) void*)g,
      (__attribute__((address_space(3))) void*)l, 16, 0, 0);
}

#define LGKM0() asm volatile("s_waitcnt lgkmcnt(0)" ::: "memory")
#define VMC(n)  asm volatile("s_waitcnt vmcnt(" #n ")" ::: "memory")
#define SBAR()  __builtin_amdgcn_s_barrier()
#define SCH0()  __builtin_amdgcn_sched_barrier(0)

// ---------------------------------------------------------------------------
// cast_kernel: block roles.
//   bid <1024 : x fp32 -> xh bf16 (pure stream)
//   1024-2047 : Wd [E,D,H] -> bdh[(e*128+h)][d] bf16 (32x32 LDS transpose)
//   2048-3071 : Wu [E,H,D] -> wuh[d][(e*128+h)] bf16
//   3072      : Wr [D,8] -> wrt[16][1024] bf16 (rows 8..15 zero)
// ---------------------------------------------------------------------------
__global__ __launch_bounds__(256) void cast_kernel(
    const float* __restrict__ x, const float* __restrict__ Wr,
    const float* __restrict__ Wd, const float* __restrict__ Wu,
    u16* __restrict__ xh, u16* __restrict__ wrt,
    u16* __restrict__ bdh, u16* __restrict__ wuh)
{
  const int bid = blockIdx.x;
  if (bid < 1024) {
    const int base = bid * 256 + threadIdx.x;
#pragma unroll
    for (int k = 0; k < 16; ++k) {
      const size_t i = (size_t)base + (size_t)k * 262144;
      float4 v = ((const float4*)x)[i];
      ((ushort4*)xh)[i] = make_ushort4(f2bf(v.x), f2bf(v.y), f2bf(v.z), f2bf(v.w));
    }
    return;
  }
  if (bid >= 3072) {
    for (int i = threadIdx.x; i < 16384; i += 256) {
      const int e = i >> 10, d = i & 1023;
      wrt[i] = (e < 8) ? f2bf(Wr[d * 8 + e]) : (u16)0;
    }
    return;
  }
  __shared__ float tl[32][33];
  const float* src; u16* dst; int C; size_t dbase; int c0, r0;
  if (bid < 2048) {
    const int l = bid - 1024, e = l >> 7;
    src = Wd + (size_t)e * DDIM * 128; C = 128;
    dst = bdh; dbase = (size_t)e * 128 * 1024;
    c0 = (l & 3) * 32; r0 = ((l >> 2) & 31) * 32;
  } else {
    const int l = bid - 2048, e = l >> 7;
    src = Wu + (size_t)e * 128 * DDIM; C = DDIM;
    dst = wuh; dbase = (size_t)e * 128;
    c0 = (l & 31) * 32; r0 = ((l >> 5) & 3) * 32;
  }
  const int tx = threadIdx.x & 31, ty = threadIdx.x >> 5;
#pragma unroll
  for (int i = 0; i < 4; ++i)
    tl[ty + i * 8][tx] = src[(size_t)(r0 + ty + i * 8) * C + c0 + tx];
  __syncthreads();
#pragma unroll
  for (int i = 0; i < 4; ++i)
    dst[dbase + (size_t)(c0 + ty + i * 8) * 1024 + r0 + tx] = f2bf(tl[tx][ty + i * 8]);
}

// ---------------------------------------------------------------------------
// router_kernel: probs = softmax(x @ Wr + br). Block = 64 tokens, 4 waves
// split K (256 each), MFMA vs wrt[16][1024], LDS reduce, softmax.
// ---------------------------------------------------------------------------
__global__ __launch_bounds__(256) void router_kernel(
    const u16* __restrict__ xh, const u16* __restrict__ wrt,
    const float* __restrict__ br, float* __restrict__ probs)
{
  __shared__ float red[4][64][16];
  const int wave = threadIdx.x >> 6, lane = threadIdx.x & 63;
  const int fr = lane & 15, fq = lane >> 4;
  const int t0 = blockIdx.x * 64;
  const int k0 = wave * 256;

  f32x4 acc[4] = {};
#pragma unroll
  for (int ks = 0; ks < 8; ++ks) {
    const int kc = k0 + ks * 32 + fq * 8;
    bf16x8 b = *(const bf16x8*)&wrt[fr * 1024 + kc];
#pragma unroll
    for (int mi = 0; mi < 4; ++mi) {
      bf16x8 a = *(const bf16x8*)&xh[(size_t)(t0 + mi * 16 + fr) * 1024 + kc];
      acc[mi] = __builtin_amdgcn_mfma_f32_16x16x32_bf16(a, b, acc[mi], 0, 0, 0);
    }
  }
#pragma unroll
  for (int mi = 0; mi < 4; ++mi)
#pragma unroll
    for (int j = 0; j < 4; ++j)
      red[wave][mi * 16 + fq * 4 + j][fr] = acc[mi][j];
  __syncthreads();
  const int row = threadIdx.x;
  if (row < 64) {
    float lg[8], mx = -1e30f;
#pragma unroll
    for (int e = 0; e < 8; ++e) {
      float v = red[0][row][e] + red[1][row][e] + red[2][row][e] + red[3][row][e] + br[e];
      lg[e] = v; mx = fmaxf(mx, v);
    }
    float s = 0.f;
#pragma unroll
    for (int e = 0; e < 8; ++e) { lg[e] = expf(lg[e] - mx); s += lg[e]; }
    const float inv = 1.f / s;
#pragma unroll
    for (int e = 0; e < 8; ++e) probs[(size_t)(t0 + row) * 8 + e] = lg[e] * inv;
  }
}

// ---------------------------------------------------------------------------
// 8-phase GEMM (m201-style): C[16384,1024] = A[M,K] * B^T[N,K], bf16.
// BM=BN=256, BK=64, 8 waves (2M x 4N), 128 KiB LDS double-buffer.
// Buffer layout (64KB each): A0|A1|B0|B1 halves of 16KB ([128][64] bf16).
// Phase reads: P0 A-lo(8)+B-lo(4), P1 B-hi(4), P2 A-hi(8), P3 none (regs held).
// Stage stream: P0 A0(t+1), P1 A1(t+1), P2 B0(t+2), P3 B1(t+2); vmcnt(4) @P3.
// Region safety: each stage lands >=1 barrier-pair after last read of region.
// EPI=0: gp = probs[m, n>>7] * gelu(acc + bd[n]) -> bf16
// EPI=1: out = acc + sum_e probs[m,e]*bu[e,n]    -> fp32
// ---------------------------------------------------------------------------
#define MFMA(a, b, c) __builtin_amdgcn_mfma_f32_16x16x32_bf16(a, b, c, 0, 0, 0)

template <int EPI>
__global__ __launch_bounds__(512, 2) void gemm8_kernel(
    const u16* __restrict__ A, const u16* __restrict__ Bm,
    const float* __restrict__ bias, const float* __restrict__ probs,
    u16* __restrict__ ogp, float* __restrict__ of)
{
  __shared__ __align__(128) char lds[131072];
  const int tid = threadIdx.x, lane = tid & 63, wave = tid >> 6;
  const int wm = wave >> 2, wn = wave & 3;         // 2 M-waves x 4 N-waves
  const int fr = lane & 15, fq = lane >> 4;

  // XCD-chunked mapping: 256 blocks, 8 XCDs x 32 contiguous wgids.
  const int wg = (blockIdx.x & 7) * 32 + (blockIdx.x >> 3);
  const int n0 = (wg >> 6) * 256;
  const int m0 = (wg & 63) * 256;

  auto stage = [&](int t, int r) {   // r: 0=A0 1=A1 2=B0 3=B1
    if (t >= NKT) return;
    char* dst = lds + (t & 1) * 65536 + r * 16384;
    const u16* src = (r < 2) ? A : Bm;
    const int rbase = ((r < 2) ? m0 : n0) + (r & 1) * 128;
    const int kt = t * BK;
#pragma unroll
    for (int i = 0; i < 2; ++i) {
      const int off = i * 8192 + tid * 16;
      const int row = off >> 7;
      const int sc = ((off >> 4) & 7) ^ (row & 7);
      async16(src + (size_t)(rbase + row) * DDIM + kt + sc * 8, dst + off);
    }
  };
  auto ldsA = [&](int t, int mi, int k2) {
    const int ar = wm * 128 + mi * 16 + fr;
    const int off = (t & 1) * 65536 + (ar >> 7) * 16384 + (ar & 127) * 128
                  + ((((k2 << 2) + fq) ^ (ar & 7)) << 4);
    return *(const bf16x8*)(lds + off);
  };
  auto ldsB = [&](int t, int ni, int k2) {
    const int brr = wn * 64 + ni * 16 + fr;
    const int off = (t & 1) * 65536 + 32768 + (brr >> 7) * 16384 + (brr & 127) * 128
                  + ((((k2 << 2) + fq) ^ (brr & 7)) << 4);
    return *(const bf16x8*)(lds + off);
  };

  f32x4 acc[8][4] = {};

  // Prologue: tile0 all 4 halves + tile1's B halves; tile0 landed (vmcnt(4)).
  stage(0, 0); stage(0, 1); stage(0, 2); stage(0, 3);
  stage(1, 2); stage(1, 3);
  VMC(4); SBAR(); SCH0();

#pragma unroll 2
  for (int t = 0; t < NKT; ++t) {
    bf16x8 af[2][4], blo[2][2], bhi[2][2];
    // ---- P0: read A-lo + B-lo; stage A0(t+1); MFMA (mi0-3 x ni0-1) ----
#pragma unroll
    for (int k2 = 0; k2 < 2; ++k2) {
#pragma unroll
      for (int mi = 0; mi < 4; ++mi) af[k2][mi] = ldsA(t, mi, k2);
#pragma unroll
      for (int ni = 0; ni < 2; ++ni) blo[k2][ni] = ldsB(t, ni, k2);
    }
    stage(t + 1, 0);
    SBAR(); LGKM0(); SCH0();
    __builtin_amdgcn_s_setprio(1);
#pragma unroll
    for (int k2 = 0; k2 < 2; ++k2)
#pragma unroll
      for (int mi = 0; mi < 4; ++mi)
#pragma unroll
        for (int ni = 0; ni < 2; ++ni)
          acc[mi][ni] = MFMA(af[k2][mi], blo[k2][ni], acc[mi][ni]);
    __builtin_amdgcn_s_setprio(0);
    SBAR(); SCH0();
    // ---- P1: read B-hi; stage A1(t+1); MFMA (mi0-3 x ni2-3) ----
#pragma unroll
    for (int k2 = 0; k2 < 2; ++k2)
#pragma unroll
      for (int ni = 0; ni < 2; ++ni) bhi[k2][ni] = ldsB(t, 2 + ni, k2);
    stage(t + 1, 1);
    SBAR(); LGKM0(); SCH0();
    __builtin_amdgcn_s_setprio(1);
#pragma unroll
    for (int k2 = 0; k2 < 2; ++k2)
#pragma unroll
      for (int mi = 0; mi < 4; ++mi)
#pragma unroll
        for (int ni = 0; ni < 2; ++ni)
          acc[mi][2 + ni] = MFMA(af[k2][mi], bhi[k2][ni], acc[mi][2 + ni]);
    __builtin_amdgcn_s_setprio(0);
    SBAR(); SCH0();
    // ---- P2: read A-hi; stage B0(t+2); MFMA (mi4-7 x ni2-3) ----
#pragma unroll
    for (int k2 = 0; k2 < 2; ++k2)
#pragma unroll
      for (int mi = 0; mi < 4; ++mi) af[k2][mi] = ldsA(t, 4 + mi, k2);
    stage(t + 2, 2);
    SBAR(); LGKM0(); SCH0();
    __builtin_amdgcn_s_setprio(1);
#pragma unroll
    for (int k2 = 0; k2 < 2; ++k2)
#pragma unroll
      for (int mi = 0; mi < 4; ++mi)
#pragma unroll
        for (int ni = 0; ni < 2; ++ni)
          acc[4 + mi][2 + ni] = MFMA(af[k2][mi], bhi[k2][ni], acc[4 + mi][2 + ni]);
    __builtin_amdgcn_s_setprio(0);
    SBAR(); SCH0();
    // ---- P3: stage B1(t+2); counted vmcnt; MFMA (mi4-7 x ni0-1) ----
    stage(t + 2, 3);
    if (t < NKT - 2) { VMC(4); } else { VMC(0); }
    SBAR(); SCH0();
    __builtin_amdgcn_s_setprio(1);
#pragma unroll
    for (int k2 = 0; k2 < 2; ++k2)
#pragma unroll
      for (int mi = 0; mi < 4; ++mi)
#pragma unroll
        for (int ni = 0; ni < 2; ++ni)
          acc[4 + mi][ni] = MFMA(af[k2][mi], blo[k2][ni], acc[4 + mi][ni]);
    __builtin_amdgcn_s_setprio(0);
    SBAR(); SCH0();
  }

  if (EPI == 0) {
    const int e = (n0 + wn * 64) >> 7;
#pragma unroll
    for (int mi = 0; mi < 8; ++mi)
#pragma unroll
      for (int ni = 0; ni < 4; ++ni) {
        const int col = n0 + wn * 64 + ni * 16 + fr;
        const float bv = bias[col];
#pragma unroll
        for (int j = 0; j < 4; ++j) {
          const int row = m0 + wm * 128 + mi * 16 + fq * 4 + j;
          float v = acc[mi][ni][j] + bv;
          float g = 0.5f * v * (1.0f + erff(v * 0.70710678118654752f));
          ogp[(size_t)row * DDIM + col] = f2bf(probs[(size_t)row * 8 + e] * g);
        }
      }
  } else {
    float buv[4][8];
#pragma unroll
    for (int ni = 0; ni < 4; ++ni) {
      const int col = n0 + wn * 64 + ni * 16 + fr;
#pragma unroll
      for (int e = 0; e < 8; ++e) buv[ni][e] = bias[e * 1024 + col];
    }
#pragma unroll
    for (int mi = 0; mi < 8; ++mi)
#pragma unroll
      for (int j = 0; j < 4; ++j) {
        const int row = m0 + wm * 128 + mi * 16 + fq * 4 + j;
        const float4* pp = (const float4*)(probs + (size_t)row * 8);
        float4 p0 = pp[0], p1 = pp[1];
        float pr[8] = {p0.x, p0.y, p0.z, p0.w, p1.x, p1.y, p1.z, p1.w};
#pragma unroll
        for (int ni = 0; ni < 4; ++ni) {
          float v = acc[mi][ni][j];
#pragma unroll
          for (int e = 0; e < 8; ++e) v += pr[e] * buv[ni][e];
          of[(size_t)row * DDIM + n0 + wn * 64 + ni * 16 + fr] = v;
        }
      }
  }
}

// ---------------------------------------------------------------------------
extern "C" void kernel_launch(void* const* d_in, const int* in_sizes, int n_in,
                              void* d_out, int out_size, void* d_ws, size_t ws_size,
                              hipStream_t stream)
{
  const float* x  = (const float*)d_in[0];
  const float* Wr = (const float*)d_in[1];
  const float* br = (const float*)d_in[2];
  const float* Wd = (const float*)d_in[3];
  const float* bd = (const float*)d_in[4];
  const float* Wu = (const float*)d_in[5];
  const float* bu = (const float*)d_in[6];
  float* out = (float*)d_out;

  char* ws = (char*)d_ws;
  size_t off = 0;
  auto alloc = [&](size_t bytes) -> void* {
    void* p = ws + off;
    off += (bytes + 255) & ~(size_t)255;
    return p;
  };
  u16* xh  = (u16*)alloc((size_t)MTOK * DDIM * 2);
  u16* gph = (u16*)alloc((size_t)MTOK * 1024 * 2);
  u16* bdh = (u16*)alloc((size_t)1024 * 1024 * 2);
  u16* wuh = (u16*)alloc((size_t)1024 * 1024 * 2);
  u16* wrt = (u16*)alloc((size_t)16 * 1024 * 2);
  float* probs = (float*)alloc((size_t)MTOK * 8 * 4);
  (void)ws_size; (void)in_sizes; (void)n_in; (void)out_size;

  cast_kernel<<<3073, 256, 0, stream>>>(x, Wr, Wd, Wu, xh, wrt, bdh, wuh);
  router_kernel<<<MTOK / 64, 256, 0, stream>>>(xh, wrt, br, probs);
  gemm8_kernel<0><<<256, 512, 0, stream>>>(xh, bdh, bd, probs, gph, nullptr);
  gemm8_kernel<1><<<256, 512, 0, stream>>>(gph, wuh, bu, probs, nullptr, out);
}

// Round 6
// 233.415 us; speedup vs baseline: 1.6981x; 1.0368x over previous
//
#include <hip/hip_runtime.h>

#define DEV __device__ __forceinline__

typedef short bf16x8 __attribute__((ext_vector_type(8)));
typedef float f32x4  __attribute__((ext_vector_type(4)));
typedef unsigned short u16;
typedef unsigned int u32;

constexpr int MTOK = 16384;
constexpr int DDIM = 1024;
constexpr int BK = 64;
constexpr int NKT = DDIM / BK;   // 16

DEV u16 f2bf(float f) {
  u32 u = __builtin_bit_cast(u32, f);
  return (u16)((u + 0x7FFFu + ((u >> 16) & 1u)) >> 16);
}

DEV void async16(const void* g, void* l) {
  __builtin_amdgcn_global_load_lds(
      (const __attribute__((address_space(1))) void*)g,
      (__attribute__((address_space(3))) void*)l, 16, 0, 0);
}

#define LGKM0() asm volatile("s_waitcnt lgkmcnt(0)" ::: "memory")
#define VMC(n)  asm volatile("s_waitcnt vmcnt(" #n ")" ::: "memory")
#define SBAR()  __builtin_amdgcn_s_barrier()
#define SCH0()  __builtin_amdgcn_sched_barrier(0)

// ---------------------------------------------------------------------------
// cast_kernel: block roles.
//   bid <1024 : x fp32 -> xh bf16 (pure stream)
//   1024-2047 : Wd [E,D,H] -> bdh[(e*128+h)][d] bf16 (32x32 LDS transpose)
//   2048-3071 : Wu [E,H,D] -> wuh[d][(e*128+h)] bf16
//   3072      : Wr [D,8] -> wrt[16][1024] bf16 (rows 8..15 zero)
// ---------------------------------------------------------------------------
__global__ __launch_bounds__(256) void cast_kernel(
    const float* __restrict__ x, const float* __restrict__ Wr,
    const float* __restrict__ Wd, const float* __restrict__ Wu,
    u16* __restrict__ xh, u16* __restrict__ wrt,
    u16* __restrict__ bdh, u16* __restrict__ wuh)
{
  const int bid = blockIdx.x;
  if (bid < 1024) {
    const int base = bid * 256 + threadIdx.x;
#pragma unroll
    for (int k = 0; k < 16; ++k) {
      const size_t i = (size_t)base + (size_t)k * 262144;
      float4 v = ((const float4*)x)[i];
      ((ushort4*)xh)[i] = make_ushort4(f2bf(v.x), f2bf(v.y), f2bf(v.z), f2bf(v.w));
    }
    return;
  }
  if (bid >= 3072) {
    for (int i = threadIdx.x; i < 16384; i += 256) {
      const int e = i >> 10, d = i & 1023;
      wrt[i] = (e < 8) ? f2bf(Wr[d * 8 + e]) : (u16)0;
    }
    return;
  }
  __shared__ float tl[32][33];
  const float* src; u16* dst; int C; size_t dbase; int c0, r0;
  if (bid < 2048) {
    const int l = bid - 1024, e = l >> 7;
    src = Wd + (size_t)e * DDIM * 128; C = 128;
    dst = bdh; dbase = (size_t)e * 128 * 1024;
    c0 = (l & 3) * 32; r0 = ((l >> 2) & 31) * 32;
  } else {
    const int l = bid - 2048, e = l >> 7;
    src = Wu + (size_t)e * 128 * DDIM; C = DDIM;
    dst = wuh; dbase = (size_t)e * 128;
    c0 = (l & 31) * 32; r0 = ((l >> 5) & 3) * 32;
  }
  const int tx = threadIdx.x & 31, ty = threadIdx.x >> 5;
#pragma unroll
  for (int i = 0; i < 4; ++i)
    tl[ty + i * 8][tx] = src[(size_t)(r0 + ty + i * 8) * C + c0 + tx];
  __syncthreads();
#pragma unroll
  for (int i = 0; i < 4; ++i)
    dst[dbase + (size_t)(c0 + ty + i * 8) * 1024 + r0 + tx] = f2bf(tl[tx][ty + i * 8]);
}

// ---------------------------------------------------------------------------
// router_kernel: probs = softmax(x @ Wr + br). Block = 64 tokens, 4 waves
// split K (256 each), MFMA vs wrt[16][1024], LDS reduce, softmax.
// ---------------------------------------------------------------------------
__global__ __launch_bounds__(256) void router_kernel(
    const u16* __restrict__ xh, const u16* __restrict__ wrt,
    const float* __restrict__ br, float* __restrict__ probs)
{
  __shared__ float red[4][64][16];
  const int wave = threadIdx.x >> 6, lane = threadIdx.x & 63;
  const int fr = lane & 15, fq = lane >> 4;
  const int t0 = blockIdx.x * 64;
  const int k0 = wave * 256;

  f32x4 acc[4] = {};
#pragma unroll
  for (int ks = 0; ks < 8; ++ks) {
    const int kc = k0 + ks * 32 + fq * 8;
    bf16x8 b = *(const bf16x8*)&wrt[fr * 1024 + kc];
#pragma unroll
    for (int mi = 0; mi < 4; ++mi) {
      bf16x8 a = *(const bf16x8*)&xh[(size_t)(t0 + mi * 16 + fr) * 1024 + kc];
      acc[mi] = __builtin_amdgcn_mfma_f32_16x16x32_bf16(a, b, acc[mi], 0, 0, 0);
    }
  }
#pragma unroll
  for (int mi = 0; mi < 4; ++mi)
#pragma unroll
    for (int j = 0; j < 4; ++j)
      red[wave][mi * 16 + fq * 4 + j][fr] = acc[mi][j];
  __syncthreads();
  const int row = threadIdx.x;
  if (row < 64) {
    float lg[8], mx = -1e30f;
#pragma unroll
    for (int e = 0; e < 8; ++e) {
      float v = red[0][row][e] + red[1][row][e] + red[2][row][e] + red[3][row][e] + br[e];
      lg[e] = v; mx = fmaxf(mx, v);
    }
    float s = 0.f;
#pragma unroll
    for (int e = 0; e < 8; ++e) { lg[e] = expf(lg[e] - mx); s += lg[e]; }
    const float inv = 1.f / s;
#pragma unroll
    for (int e = 0; e < 8; ++e) probs[(size_t)(t0 + row) * 8 + e] = lg[e] * inv;
  }
}

// ---------------------------------------------------------------------------
// 8-phase GEMM: C[16384,1024] = A[M,K] * B^T[N,K], bf16.
// BM=BN=256, BK=64, 8 waves (2M x 4N), 128 KiB LDS double-buffer.
// Region retirement (all waves, barrier-synced): B of tile t fully read by
// end-of-P1(t) barrier; A by end-of-P2(t). So same-parity staging is safe:
//   P2(t): stage B0,B1(t+2)   (B region idle since P1-end)
//   P3(t): stage A0,A1(t+2)   (A region idle since P2-end)
// One vmcnt(8) per K-tile at P3-end: 8 newest = tile t+2's loads, so all of
// tile t+1 is forced landed; issue->consume distance ~6-9 phases (covers
// ~900cy HBM latency).
// XCD map: xcd=bid&7 owns M-tiles [8*xcd,8*xcd+8) x all 4 N-tiles ->
// per-XCD A working set 4MB (=L2) + B 2MB.
// EPI=0: gp = probs[m, n>>7] * gelu(acc + bd[n]) -> bf16
// EPI=1: out = acc + sum_e probs[m,e]*bu[e,n]    -> fp32
// ---------------------------------------------------------------------------
#define MFMA(a, b, c) __builtin_amdgcn_mfma_f32_16x16x32_bf16(a, b, c, 0, 0, 0)

template <int EPI>
__global__ __launch_bounds__(512, 2) void gemm8_kernel(
    const u16* __restrict__ A, const u16* __restrict__ Bm,
    const float* __restrict__ bias, const float* __restrict__ probs,
    u16* __restrict__ ogp, float* __restrict__ of)
{
  __shared__ __align__(128) char lds[131072];
  const int tid = threadIdx.x, lane = tid & 63, wave = tid >> 6;
  const int wm = wave >> 2, wn = wave & 3;         // 2 M-waves x 4 N-waves
  const int fr = lane & 15, fq = lane >> 4;

  // XCD-owned M-panels: same-A blocks co-resident on one XCD.
  const int xcd = blockIdx.x & 7, idx = blockIdx.x >> 3;
  const int m0 = (xcd * 8 + (idx & 7)) * 256;
  const int n0 = (idx >> 3) * 256;

  auto stage = [&](int t, int r) {   // r: 0=A0 1=A1 2=B0 3=B1
    if (t >= NKT) return;
    char* dst = lds + (t & 1) * 65536 + r * 16384;
    const u16* src = (r < 2) ? A : Bm;
    const int rbase = ((r < 2) ? m0 : n0) + (r & 1) * 128;
    const int kt = t * BK;
#pragma unroll
    for (int i = 0; i < 2; ++i) {
      const int off = i * 8192 + tid * 16;
      const int row = off >> 7;
      const int sc = ((off >> 4) & 7) ^ (row & 7);
      async16(src + (size_t)(rbase + row) * DDIM + kt + sc * 8, dst + off);
    }
  };
  auto ldsA = [&](int t, int mi, int k2) {
    const int ar = wm * 128 + mi * 16 + fr;
    const int off = (t & 1) * 65536 + (ar >> 7) * 16384 + (ar & 127) * 128
                  + ((((k2 << 2) + fq) ^ (ar & 7)) << 4);
    return *(const bf16x8*)(lds + off);
  };
  auto ldsB = [&](int t, int ni, int k2) {
    const int brr = wn * 64 + ni * 16 + fr;
    const int off = (t & 1) * 65536 + 32768 + (brr >> 7) * 16384 + (brr & 127) * 128
                  + ((((k2 << 2) + fq) ^ (brr & 7)) << 4);
    return *(const bf16x8*)(lds + off);
  };

  f32x4 acc[8][4] = {};

  // Prologue: tiles 0 and 1 fully staged; vmcnt(8) -> tile 0 landed.
  stage(0, 0); stage(0, 1); stage(0, 2); stage(0, 3);
  stage(1, 0); stage(1, 1); stage(1, 2); stage(1, 3);
  VMC(8); SBAR(); SCH0();

#pragma unroll 2
  for (int t = 0; t < NKT; ++t) {
    bf16x8 af[2][4], blo[2][2], bhi[2][2];
    // ---- P0: read A-lo + B-lo; MFMA (mi0-3 x ni0-1) ----
#pragma unroll
    for (int k2 = 0; k2 < 2; ++k2) {
#pragma unroll
      for (int mi = 0; mi < 4; ++mi) af[k2][mi] = ldsA(t, mi, k2);
#pragma unroll
      for (int ni = 0; ni < 2; ++ni) blo[k2][ni] = ldsB(t, ni, k2);
    }
    SBAR(); LGKM0(); SCH0();
    __builtin_amdgcn_s_setprio(1);
#pragma unroll
    for (int k2 = 0; k2 < 2; ++k2)
#pragma unroll
      for (int mi = 0; mi < 4; ++mi)
#pragma unroll
        for (int ni = 0; ni < 2; ++ni)
          acc[mi][ni] = MFMA(af[k2][mi], blo[k2][ni], acc[mi][ni]);
    __builtin_amdgcn_s_setprio(0);
    SBAR(); SCH0();
    // ---- P1: read B-hi; MFMA (mi0-3 x ni2-3) ----
#pragma unroll
    for (int k2 = 0; k2 < 2; ++k2)
#pragma unroll
      for (int ni = 0; ni < 2; ++ni) bhi[k2][ni] = ldsB(t, 2 + ni, k2);
    SBAR(); LGKM0(); SCH0();
    __builtin_amdgcn_s_setprio(1);
#pragma unroll
    for (int k2 = 0; k2 < 2; ++k2)
#pragma unroll
      for (int mi = 0; mi < 4; ++mi)
#pragma unroll
        for (int ni = 0; ni < 2; ++ni)
          acc[mi][2 + ni] = MFMA(af[k2][mi], bhi[k2][ni], acc[mi][2 + ni]);
    __builtin_amdgcn_s_setprio(0);
    SBAR(); SCH0();
    // ---- P2: read A-hi; stage B0,B1(t+2) (B region idle since P1-end);
    //          MFMA (mi4-7 x ni2-3) ----
#pragma unroll
    for (int k2 = 0; k2 < 2; ++k2)
#pragma unroll
      for (int mi = 0; mi < 4; ++mi) af[k2][mi] = ldsA(t, 4 + mi, k2);
    stage(t + 2, 2); stage(t + 2, 3);
    SBAR(); LGKM0(); SCH0();
    __builtin_amdgcn_s_setprio(1);
#pragma unroll
    for (int k2 = 0; k2 < 2; ++k2)
#pragma unroll
      for (int mi = 0; mi < 4; ++mi)
#pragma unroll
        for (int ni = 0; ni < 2; ++ni)
          acc[4 + mi][2 + ni] = MFMA(af[k2][mi], bhi[k2][ni], acc[4 + mi][2 + ni]);
    __builtin_amdgcn_s_setprio(0);
    SBAR(); SCH0();
    // ---- P3: stage A0,A1(t+2) (A region idle since P2-end); vmcnt(8) ->
    //          tile t+1 landed; MFMA (mi4-7 x ni0-1) ----
    stage(t + 2, 0); stage(t + 2, 1);
    if (t < NKT - 2) { VMC(8); } else { VMC(0); }
    SBAR(); SCH0();
    __builtin_amdgcn_s_setprio(1);
#pragma unroll
    for (int k2 = 0; k2 < 2; ++k2)
#pragma unroll
      for (int mi = 0; mi < 4; ++mi)
#pragma unroll
        for (int ni = 0; ni < 2; ++ni)
          acc[4 + mi][ni] = MFMA(af[k2][mi], blo[k2][ni], acc[4 + mi][ni]);
    __builtin_amdgcn_s_setprio(0);
    SBAR(); SCH0();
  }

  if (EPI == 0) {
    const int e = (n0 + wn * 64) >> 7;
#pragma unroll
    for (int mi = 0; mi < 8; ++mi)
#pragma unroll
      for (int ni = 0; ni < 4; ++ni) {
        const int col = n0 + wn * 64 + ni * 16 + fr;
        const float bv = bias[col];
#pragma unroll
        for (int j = 0; j < 4; ++j) {
          const int row = m0 + wm * 128 + mi * 16 + fq * 4 + j;
          float v = acc[mi][ni][j] + bv;
          float g = 0.5f * v * (1.0f + erff(v * 0.70710678118654752f));
          ogp[(size_t)row * DDIM + col] = f2bf(probs[(size_t)row * 8 + e] * g);
        }
      }
  } else {
    float buv[4][8];
#pragma unroll
    for (int ni = 0; ni < 4; ++ni) {
      const int col = n0 + wn * 64 + ni * 16 + fr;
#pragma unroll
      for (int e = 0; e < 8; ++e) buv[ni][e] = bias[e * 1024 + col];
    }
#pragma unroll
    for (int mi = 0; mi < 8; ++mi)
#pragma unroll
      for (int j = 0; j < 4; ++j) {
        const int row = m0 + wm * 128 + mi * 16 + fq * 4 + j;
        const float4* pp = (const float4*)(probs + (size_t)row * 8);
        float4 p0 = pp[0], p1 = pp[1];
        float pr[8] = {p0.x, p0.y, p0.z, p0.w, p1.x, p1.y, p1.z, p1.w};
#pragma unroll
        for (int ni = 0; ni < 4; ++ni) {
          float v = acc[mi][ni][j];
#pragma unroll
          for (int e = 0; e < 8; ++e) v += pr[e] * buv[ni][e];
          of[(size_t)row * DDIM + n0 + wn * 64 + ni * 16 + fr] = v;
        }
      }
  }
}

// ---------------------------------------------------------------------------
extern "C" void kernel_launch(void* const* d_in, const int* in_sizes, int n_in,
                              void* d_out, int out_size, void* d_ws, size_t ws_size,
                              hipStream_t stream)
{
  const float* x  = (const float*)d_in[0];
  const float* Wr = (const float*)d_in[1];
  const float* br = (const float*)d_in[2];
  const float* Wd = (const float*)d_in[3];
  const float* bd = (const float*)d_in[4];
  const float* Wu = (const float*)d_in[5];
  const float* bu = (const float*)d_in[6];
  float* out = (float*)d_out;

  char* ws = (char*)d_ws;
  size_t off = 0;
  auto alloc = [&](size_t bytes) -> void* {
    void* p = ws + off;
    off += (bytes + 255) & ~(size_t)255;
    return p;
  };
  u16* xh  = (u16*)alloc((size_t)MTOK * DDIM * 2);
  u16* gph = (u16*)alloc((size_t)MTOK * 1024 * 2);
  u16* bdh = (u16*)alloc((size_t)1024 * 1024 * 2);
  u16* wuh = (u16*)alloc((size_t)1024 * 1024 * 2);
  u16* wrt = (u16*)alloc((size_t)16 * 1024 * 2);
  float* probs = (float*)alloc((size_t)MTOK * 8 * 4);
  (void)ws_size; (void)in_sizes; (void)n_in; (void)out_size;

  cast_kernel<<<3073, 256, 0, stream>>>(x, Wr, Wd, Wu, xh, wrt, bdh, wuh);
  router_kernel<<<MTOK / 64, 256, 0, stream>>>(xh, wrt, br, probs);
  gemm8_kernel<0><<<256, 512, 0, stream>>>(xh, bdh, bd, probs, gph, nullptr);
  gemm8_kernel<1><<<256, 512, 0, stream>>>(gph, wuh, bu, probs, nullptr, out);
}